// Round 1
// baseline (1515.501 us; speedup 1.0000x reference)
//
#include <hip/hip_runtime.h>
#include <hip/hip_bf16.h>

typedef __attribute__((ext_vector_type(8))) short bf16x8;
typedef __attribute__((ext_vector_type(4))) float f32x4;

#define MROWS 200704
#define CDIM  384
#define NQKV  1152
#define NTOK  49

// ---------- helpers ----------
static __device__ __forceinline__ unsigned short f2bf(float f) {
  union { float f; unsigned u; } v; v.f = f;
  unsigned r = v.u + 0x7FFFu + ((v.u >> 16) & 1u);   // round-to-nearest-even
  return (unsigned short)(r >> 16);
}

static __device__ __forceinline__ void store_out(__hip_bfloat16* p, float v) {
  *(unsigned short*)p = f2bf(v);
}
static __device__ __forceinline__ void store_out(float* p, float v) { *p = v; }

typedef __attribute__((address_space(3))) unsigned int lds_u32_t;
typedef const __attribute__((address_space(1))) unsigned int gbl_u32_t;
#define ASYNC_COPY16(gptr, lptr) \
  __builtin_amdgcn_global_load_lds((gbl_u32_t*)(gptr), (lds_u32_t*)(lptr), 16, 0, 0)

// ---------- kernel 1a: x fp32 -> bf16 ----------
__global__ __launch_bounds__(256) void cvt_x_kernel(const float4* __restrict__ x,
                                                    ushort4* __restrict__ xb, int n4) {
  int idx = blockIdx.x * 256 + threadIdx.x;
  if (idx < n4) {
    float4 v = x[idx];
    ushort4 o;
    o.x = f2bf(v.x); o.y = f2bf(v.y); o.z = f2bf(v.z); o.w = f2bf(v.w);
    xb[idx] = o;
  }
}

// ---------- kernel 1b: transpose weights to [n][k] bf16; fuse rel-pos bias table ----------
__global__ __launch_bounds__(256) void cvt_small_kernel(
    const float* __restrict__ w_qkv, const float* __restrict__ w_proj,
    const float* __restrict__ bias_table,
    __hip_bfloat16* __restrict__ wqkv_t, __hip_bfloat16* __restrict__ wproj_t,
    float* __restrict__ bias_f) {
  int idx = blockIdx.x * 256 + threadIdx.x;
  if (idx < 442368) {                       // w_qkv: [384][1152] -> [1152][384]
    int k = idx / 1152, n = idx % 1152;
    *(unsigned short*)&wqkv_t[n * 384 + k] = f2bf(w_qkv[idx]);
  } else if (idx < 589824) {                // w_proj: [384][384] -> [384][384]^T
    int t = idx - 442368;
    int k = t / 384, n = t % 384;
    *(unsigned short*)&wproj_t[n * 384 + k] = f2bf(w_proj[t]);
  } else if (idx < 618636) {                // bias_f[h][i*49+j] = table[REL_IDX[i][j]][h]
    int t = idx - 589824;
    int h = t / 2401, ij = t % 2401;
    int i = ij / 49, j = ij % 49;
    int yi = i / 7, xi = i % 7, yj = j / 7, xj = j % 7;
    int rel = (yi - yj + 6) * 13 + (xi - xj + 6);
    bias_f[h * 2401 + ij] = bias_table[rel * 12 + h];
  }
}

// ---------- kernels 2/4: C[M][ldc] = A[M][384] @ Bt[N][384]^T + bias ----------
template <typename OUT>
__global__ __launch_bounds__(256) void gemm_bt_kernel(
    const __hip_bfloat16* __restrict__ A,   // [M][384] row-major bf16
    const __hip_bfloat16* __restrict__ Bt,  // [N][384] row-major bf16 (B transposed)
    const float* __restrict__ bias,         // [N]
    OUT* __restrict__ C, int ldc) {
  constexpr int K = 384;
  __shared__ __align__(16) __hip_bfloat16 As[128 * 64];
  __shared__ __align__(16) __hip_bfloat16 Bs[128 * 64];
  const int tid = threadIdx.x;
  const int lane = tid & 63;
  const int wave = tid >> 6;
  const int lm = lane & 15;
  const int lg = lane >> 4;
  const int wm = (wave & 1) * 64;
  const int wn = (wave >> 1) * 64;
  const long m0 = (long)blockIdx.x * 128;
  const long n0 = (long)blockIdx.y * 128;

  f32x4 acc[4][4];
  const f32x4 z4 = {0.f, 0.f, 0.f, 0.f};
#pragma unroll
  for (int i = 0; i < 4; i++)
#pragma unroll
    for (int j = 0; j < 4; j++) acc[i][j] = z4;

  for (int kt = 0; kt < K; kt += 64) {
#pragma unroll
    for (int c = 0; c < 4; c++) {
      int chunk = c * 256 + tid;         // 1024 chunks of 16B per 128x64 tile
      int row = chunk >> 3;
      int col = (chunk & 7) * 8;
      ASYNC_COPY16(A + (m0 + row) * K + kt + col, (char*)As + chunk * 16);
      ASYNC_COPY16(Bt + (n0 + row) * K + kt + col, (char*)Bs + chunk * 16);
    }
    __syncthreads();
#pragma unroll
    for (int ks = 0; ks < 2; ks++) {
      bf16x8 af[4], bf[4];
#pragma unroll
      for (int i = 0; i < 4; i++)
        af[i] = *(const bf16x8*)&As[(wm + i * 16 + lm) * 64 + ks * 32 + lg * 8];
#pragma unroll
      for (int j = 0; j < 4; j++)
        bf[j] = *(const bf16x8*)&Bs[(wn + j * 16 + lm) * 64 + ks * 32 + lg * 8];
#pragma unroll
      for (int i = 0; i < 4; i++)
#pragma unroll
        for (int j = 0; j < 4; j++)
          acc[i][j] = __builtin_amdgcn_mfma_f32_16x16x32_bf16(af[i], bf[j], acc[i][j], 0, 0, 0);
    }
    __syncthreads();
  }

#pragma unroll
  for (int j = 0; j < 4; j++) {
    int col = (int)n0 + wn + j * 16 + lm;
    float bv = bias[col];
#pragma unroll
    for (int i = 0; i < 4; i++) {
      long rowb = m0 + wm + i * 16 + lg * 4;
#pragma unroll
      for (int r = 0; r < 4; r++) {
        float v = acc[i][j][r] + bv;
        store_out(&C[(rowb + r) * ldc + col], v);
      }
    }
  }
}

// ---------- kernel 3: fused window attention ----------
__global__ __launch_bounds__(256) void attn_kernel(
    const __hip_bfloat16* __restrict__ qkv,   // [200704][1152]
    const float* __restrict__ bias_f,         // [12][2401]
    __hip_bfloat16* __restrict__ attn) {      // [200704][384]
  __shared__ __align__(16) __hip_bfloat16 Pls[4][64 * 64];   // per-wave P, 32 KB
  __shared__ __align__(16) __hip_bfloat16 Vtl[4][32 * 64];   // per-wave V^T, 16 KB
  const int tid = threadIdx.x;
  const int lane = tid & 63, wave = tid >> 6;
  const int lm = lane & 15, lg = lane >> 4;
  const long base = (long)blockIdx.x * NTOK * NQKV;
  const long obase = (long)blockIdx.x * NTOK * CDIM;
  const bf16x8 zf = {0, 0, 0, 0, 0, 0, 0, 0};
  const f32x4 z4 = {0.f, 0.f, 0.f, 0.f};
  const float scale = 0.17677669529663687f;   // 32^-0.5

  for (int hi = 0; hi < 3; hi++) {
    const int h = wave * 3 + hi;
    // --- Q (A-layout) and K (B^T-layout) fragments straight from global ---
    bf16x8 aq[4], bk[4];
#pragma unroll
    for (int i = 0; i < 4; i++) {
      int row = i * 16 + lm;
      if (row < NTOK) {
        aq[i] = *(const bf16x8*)(qkv + base + (long)row * NQKV + h * 32 + lg * 8);
        bk[i] = *(const bf16x8*)(qkv + base + (long)row * NQKV + 384 + h * 32 + lg * 8);
      } else { aq[i] = zf; bk[i] = zf; }
    }
    f32x4 s[4][4];
#pragma unroll
    for (int i = 0; i < 4; i++)
#pragma unroll
      for (int j = 0; j < 4; j++) s[i][j] = z4;
#pragma unroll
    for (int i = 0; i < 4; i++)
#pragma unroll
      for (int j = 0; j < 4; j++)
        s[i][j] = __builtin_amdgcn_mfma_f32_16x16x32_bf16(aq[i], bk[j], s[i][j], 0, 0, 0);

    // --- stage V^T into LDS (Vt[d][n]); zero-pad n>=49 ---
#pragma unroll 4
    for (int d = 0; d < 32; d++) {
      unsigned short v = 0;
      if (lane < NTOK)
        v = *(const unsigned short*)(qkv + base + (long)lane * NQKV + 768 + h * 32 + d);
      *(unsigned short*)&Vtl[wave][d * 64 + lane] = v;
    }

    // --- softmax (fp32) in C-layout; write P (bf16) ---
#pragma unroll
    for (int i = 0; i < 4; i++) {
#pragma unroll
      for (int r = 0; r < 4; r++) {
        int row = i * 16 + lg * 4 + r;
        float vj[4];
#pragma unroll
        for (int j = 0; j < 4; j++) {
          int col = j * 16 + lm;
          float xv = s[i][j][r] * scale;
          if (col < NTOK) {
            if (row < NTOK) xv += bias_f[h * 2401 + row * 49 + col];
          } else {
            xv = -1e30f;
          }
          vj[j] = xv;
        }
        float mx = fmaxf(fmaxf(vj[0], vj[1]), fmaxf(vj[2], vj[3]));
#pragma unroll
        for (int o = 8; o > 0; o >>= 1) mx = fmaxf(mx, __shfl_xor(mx, o));
        float sum = 0.f;
#pragma unroll
        for (int j = 0; j < 4; j++) { vj[j] = __expf(vj[j] - mx); sum += vj[j]; }
#pragma unroll
        for (int o = 8; o > 0; o >>= 1) sum += __shfl_xor(sum, o);
        float inv = 1.0f / sum;
#pragma unroll
        for (int j = 0; j < 4; j++)
          *(unsigned short*)&Pls[wave][row * 64 + j * 16 + lm] = f2bf(vj[j] * inv);
      }
    }
    __syncthreads();   // P/Vt visible across the wave's lanes

    // --- O = P @ V : A-frags of P from LDS, B^T-frags of V from Vt ---
    f32x4 o2[4][2];
#pragma unroll
    for (int i = 0; i < 4; i++) { o2[i][0] = z4; o2[i][1] = z4; }
#pragma unroll
    for (int ks = 0; ks < 2; ks++) {
      bf16x8 ap[4], bv[2];
#pragma unroll
      for (int i = 0; i < 4; i++)
        ap[i] = *(const bf16x8*)&Pls[wave][(i * 16 + lm) * 64 + ks * 32 + lg * 8];
#pragma unroll
      for (int j = 0; j < 2; j++)
        bv[j] = *(const bf16x8*)&Vtl[wave][(j * 16 + lm) * 64 + ks * 32 + lg * 8];
#pragma unroll
      for (int i = 0; i < 4; i++)
#pragma unroll
        for (int j = 0; j < 2; j++)
          o2[i][j] = __builtin_amdgcn_mfma_f32_16x16x32_bf16(ap[i], bv[j], o2[i][j], 0, 0, 0);
    }
    // --- store attn_out (bf16) ---
#pragma unroll
    for (int i = 0; i < 4; i++) {
#pragma unroll
      for (int r = 0; r < 4; r++) {
        int row = i * 16 + lg * 4 + r;
        if (row < NTOK) {
#pragma unroll
          for (int j = 0; j < 2; j++) {
            *(unsigned short*)&attn[obase + (long)row * CDIM + h * 32 + j * 16 + lm] =
                f2bf(o2[i][j][r]);
          }
        }
      }
    }
    __syncthreads();   // protect P/Vt before next head overwrites
  }
}

// ---------- launch ----------
extern "C" void kernel_launch(void* const* d_in, const int* in_sizes, int n_in,
                              void* d_out, int out_size, void* d_ws, size_t ws_size,
                              hipStream_t stream) {
  (void)in_sizes; (void)n_in; (void)out_size; (void)ws_size;
  const float* x          = (const float*)d_in[0];
  const float* w_qkv      = (const float*)d_in[1];
  const float* b_qkv      = (const float*)d_in[2];
  const float* w_proj     = (const float*)d_in[3];
  const float* b_proj     = (const float*)d_in[4];
  const float* bias_table = (const float*)d_in[5];
  float* out = (float*)d_out;

  // workspace layout (bytes):
  //   qkv     [200704][1152] bf16 : 0          .. 462422016
  //   xb/attn [200704][ 384] bf16 : 462422016  .. 616562688   (aliased: xb dead after QKV GEMM)
  //   wqkv_t  [1152][384]    bf16 : 616562688  .. 617447424
  //   wproj_t [ 384][384]    bf16 : 617447424  .. 617742336
  //   bias_f  [12][2401]     f32  : 617742336  .. 617857584
  char* ws = (char*)d_ws;
  __hip_bfloat16* qkv     = (__hip_bfloat16*)(ws);
  __hip_bfloat16* xb      = (__hip_bfloat16*)(ws + 462422016L);
  __hip_bfloat16* attn    = xb;
  __hip_bfloat16* wqkv_t  = (__hip_bfloat16*)(ws + 616562688L);
  __hip_bfloat16* wproj_t = (__hip_bfloat16*)(ws + 617447424L);
  float*          bias_f  = (float*)(ws + 617742336L);

  cvt_x_kernel<<<75264, 256, 0, stream>>>((const float4*)x, (ushort4*)xb, 19267584);
  cvt_small_kernel<<<2417, 256, 0, stream>>>(w_qkv, w_proj, bias_table, wqkv_t, wproj_t, bias_f);
  gemm_bt_kernel<__hip_bfloat16><<<dim3(1568, 9), 256, 0, stream>>>(xb, wqkv_t, b_qkv, qkv, NQKV);
  attn_kernel<<<4096, 256, 0, stream>>>(qkv, bias_f, attn);
  gemm_bt_kernel<float><<<dim3(1568, 3), 256, 0, stream>>>(attn, wproj_t, b_proj, out, CDIM);
}

// Round 2
// 1221.211 us; speedup vs baseline: 1.2410x; 1.2410x over previous
//
#include <hip/hip_runtime.h>
#include <hip/hip_bf16.h>

typedef __attribute__((ext_vector_type(8))) short bf16x8;
typedef __attribute__((ext_vector_type(4))) float f32x4;

#define CDIM  384
#define NQKV  1152
#define NTOK  49

// ---------- helpers ----------
static __device__ __forceinline__ unsigned short f2bf(float f) {
  union { float f; unsigned u; } v; v.f = f;
  unsigned r = v.u + 0x7FFFu + ((v.u >> 16) & 1u);   // round-to-nearest-even
  return (unsigned short)(r >> 16);
}

static __device__ __forceinline__ void store_out(__hip_bfloat16* p, float v) {
  *(unsigned short*)p = f2bf(v);
}
static __device__ __forceinline__ void store_out(float* p, float v) { *p = v; }

typedef __attribute__((address_space(3))) unsigned int lds_u32_t;
typedef const __attribute__((address_space(1))) unsigned int gbl_u32_t;
#define ASYNC_COPY16(gptr, lptr) \
  __builtin_amdgcn_global_load_lds((gbl_u32_t*)(gptr), (lds_u32_t*)(lptr), 16, 0, 0)

// ---------- kernel 1a: x fp32 -> bf16 ----------
__global__ __launch_bounds__(256) void cvt_x_kernel(const float4* __restrict__ x,
                                                    ushort4* __restrict__ xb, int n4) {
  int idx = blockIdx.x * 256 + threadIdx.x;
  if (idx < n4) {
    float4 v = x[idx];
    ushort4 o;
    o.x = f2bf(v.x); o.y = f2bf(v.y); o.z = f2bf(v.z); o.w = f2bf(v.w);
    xb[idx] = o;
  }
}

// ---------- kernel 1b: transpose weights to [n][k] bf16; build padded bias^T ----------
__global__ __launch_bounds__(256) void cvt_small_kernel(
    const float* __restrict__ w_qkv, const float* __restrict__ w_proj,
    const float* __restrict__ bias_table,
    __hip_bfloat16* __restrict__ wqkv_t, __hip_bfloat16* __restrict__ wproj_t,
    float* __restrict__ bias_p) {
  int idx = blockIdx.x * 256 + threadIdx.x;
  if (idx < 442368) {                       // w_qkv: [384][1152] -> [1152][384]
    int k = idx / 1152, n = idx % 1152;
    *(unsigned short*)&wqkv_t[n * 384 + k] = f2bf(w_qkv[idx]);
  } else if (idx < 589824) {                // w_proj: [384][384] -> [384][384]^T
    int t = idx - 442368;
    int k = t / 384, n = t % 384;
    *(unsigned short*)&wproj_t[n * 384 + k] = f2bf(w_proj[t]);
  } else if (idx < 638976) {                // bias_p[h][row 64][col 64], pad=0
    int t = idx - 589824;
    int h = t >> 12, rc = t & 4095;
    int row = rc >> 6, col = rc & 63;
    float v = 0.f;
    if (row < 49 && col < 49) {
      int yi = row / 7, xi = row % 7, yj = col / 7, xj = col % 7;
      int rel = (yi - yj + 6) * 13 + (xi - xj + 6);
      v = bias_table[rel * 12 + h];
    }
    bias_p[t] = v;
  }
}

// ---------- kernels 2/4: C[M][ldc] = A[M][384] @ Bt[N][384]^T + bias ----------
// grid: x = (m_in_group * NT + n_tile), y = m_group of 64 M-tiles (L2 reuse of A)
template <typename OUT, int NT>
__global__ __launch_bounds__(256) void gemm_bt_kernel(
    const __hip_bfloat16* __restrict__ A,   // [M][384] row-major bf16
    const __hip_bfloat16* __restrict__ Bt,  // [N][384] row-major bf16 (B transposed)
    const float* __restrict__ bias,         // [N]
    OUT* __restrict__ C, int ldc) {
  constexpr int K = 384;
  __shared__ __align__(16) __hip_bfloat16 As[128 * 64];
  __shared__ __align__(16) __hip_bfloat16 Bs[128 * 64];
  const int nt = blockIdx.x % NT;
  const int ml = blockIdx.x / NT;
  const long mtile = (long)blockIdx.y * 64 + ml;
  if (mtile >= 1568) return;
  const long m0 = mtile * 128;
  const long n0 = (long)nt * 128;
  const int tid = threadIdx.x;
  const int lane = tid & 63;
  const int wave = tid >> 6;
  const int lm = lane & 15;
  const int lg = lane >> 4;
  const int wm = (wave & 1) * 64;
  const int wn = (wave >> 1) * 64;

  f32x4 acc[4][4];
  const f32x4 z4 = {0.f, 0.f, 0.f, 0.f};
#pragma unroll
  for (int i = 0; i < 4; i++)
#pragma unroll
    for (int j = 0; j < 4; j++) acc[i][j] = z4;

  for (int kt = 0; kt < K; kt += 64) {
#pragma unroll
    for (int c = 0; c < 4; c++) {
      int chunk = c * 256 + tid;         // 1024 chunks of 16B per 128x64 tile
      int row = chunk >> 3;
      int col = (chunk & 7) * 8;
      ASYNC_COPY16(A + (m0 + row) * K + kt + col, (char*)As + chunk * 16);
      ASYNC_COPY16(Bt + (n0 + row) * K + kt + col, (char*)Bs + chunk * 16);
    }
    __syncthreads();
#pragma unroll
    for (int ks = 0; ks < 2; ks++) {
      bf16x8 af[4], bf[4];
#pragma unroll
      for (int i = 0; i < 4; i++)
        af[i] = *(const bf16x8*)&As[(wm + i * 16 + lm) * 64 + ks * 32 + lg * 8];
#pragma unroll
      for (int j = 0; j < 4; j++)
        bf[j] = *(const bf16x8*)&Bs[(wn + j * 16 + lm) * 64 + ks * 32 + lg * 8];
#pragma unroll
      for (int i = 0; i < 4; i++)
#pragma unroll
        for (int j = 0; j < 4; j++)
          acc[i][j] = __builtin_amdgcn_mfma_f32_16x16x32_bf16(af[i], bf[j], acc[i][j], 0, 0, 0);
    }
    __syncthreads();
  }

#pragma unroll
  for (int j = 0; j < 4; j++) {
    int col = (int)n0 + wn + j * 16 + lm;
    float bv = bias[col];
#pragma unroll
    for (int i = 0; i < 4; i++) {
      long rowb = m0 + wm + i * 16 + lg * 4;
#pragma unroll
      for (int r = 0; r < 4; r++) {
        float v = acc[i][j][r] + bv;
        store_out(&C[(rowb + r) * ldc + col], v);
      }
    }
  }
}

// ---------- kernel 3: fused window attention, one (window,head) per wave ----------
// S^T = K·Q^T so softmax rows are lane-local (in-lane reduce + 2 shuffles).
// All LDS is wave-private: NO __syncthreads anywhere.
__global__ __launch_bounds__(256, 3) void attn_kernel(
    const __hip_bfloat16* __restrict__ qkv,   // [200704][1152]
    const float* __restrict__ bias_p,         // [12][64][64] fp32, pad=0
    __hip_bfloat16* __restrict__ attn) {      // [200704][384]
  // P: [chunk=a>>3][row b 0..63][a&7] u16  (b128-readable A-fragments)
  __shared__ __align__(16) unsigned short Pls[4][4096];   // 8 KB/wave
  __shared__ __align__(16) unsigned short Vls[4][2560];   // [token 64][40] 5 KB/wave
  const int tid = threadIdx.x;
  const int lane = tid & 63, wave = tid >> 6;
  const int lm = lane & 15, lg = lane >> 4;
  const int window = blockIdx.x / 3;
  const int h = (blockIdx.x % 3) * 4 + wave;
  const long base = (long)window * NTOK * NQKV;
  const long obase = (long)window * NTOK * CDIM;
  unsigned short* P = Pls[wave];
  unsigned short* V = Vls[wave];
  const bf16x8 zf = {0, 0, 0, 0, 0, 0, 0, 0};
  const f32x4 z4 = {0.f, 0.f, 0.f, 0.f};
  const float scale = 0.17677669529663687f;   // 32^-0.5

  // --- K (A-frag) / Q (B-frag) straight from global; OOB rows>=49 read
  // neighbor-window garbage, masked/discarded downstream ---
  const __hip_bfloat16* qp = qkv + base + h * 32 + lg * 8;
  bf16x8 ak[4], bq[4];
#pragma unroll
  for (int i = 0; i < 4; i++) {
    ak[i] = *(const bf16x8*)(qp + 384 + (long)(i * 16 + lm) * NQKV);  // K rows
    bq[i] = *(const bf16x8*)(qp +       (long)(i * 16 + lm) * NQKV);  // Q rows
  }

  // --- stage V coalesced into LDS [token][40]; zero-pad tokens>=49 ---
#pragma unroll
  for (int c = 0; c < 4; c++) {
    int row = c * 16 + (lane >> 2), seg = lane & 3;
    bf16x8 v = zf;
    if (row < NTOK)
      v = *(const bf16x8*)(qkv + base + (long)row * NQKV + 768 + h * 32 + seg * 8);
    *(bf16x8*)&V[row * 40 + seg * 8] = v;
  }

  // --- S^T = K·Q^T : s[i][j][r] = S[b=j*16+lm][a=i*16+lg*4+r] ---
  f32x4 s[4][4];
#pragma unroll
  for (int i = 0; i < 4; i++)
#pragma unroll
    for (int j = 0; j < 4; j++) s[i][j] = z4;
#pragma unroll
  for (int i = 0; i < 4; i++)
#pragma unroll
    for (int j = 0; j < 4; j++)
      s[i][j] = __builtin_amdgcn_mfma_f32_16x16x32_bf16(ak[i], bq[j], s[i][j], 0, 0, 0);

  // --- softmax: row b = j*16+lm is lane-local across i,r; reduce over lg ---
#pragma unroll
  for (int j = 0; j < 4; j++) {
    const int b = j * 16 + lm;
    float l[4][4];
#pragma unroll
    for (int i = 0; i < 4; i++) {
      const float4 b4 = *(const float4*)&bias_p[h * 4096 + b * 64 + i * 16 + lg * 4];
      const float bb[4] = {b4.x, b4.y, b4.z, b4.w};
#pragma unroll
      for (int r = 0; r < 4; r++) {
        int a = i * 16 + lg * 4 + r;
        float v = fmaf(s[i][j][r], scale, bb[r]);
        l[i][r] = (a < NTOK) ? v : -1e30f;
      }
    }
    float mx = l[0][0];
#pragma unroll
    for (int i = 0; i < 4; i++)
#pragma unroll
      for (int r = 0; r < 4; r++) mx = fmaxf(mx, l[i][r]);
    mx = fmaxf(mx, __shfl_xor(mx, 16));
    mx = fmaxf(mx, __shfl_xor(mx, 32));
    float sum = 0.f;
#pragma unroll
    for (int i = 0; i < 4; i++)
#pragma unroll
      for (int r = 0; r < 4; r++) { l[i][r] = __expf(l[i][r] - mx); sum += l[i][r]; }
    sum += __shfl_xor(sum, 16);
    sum += __shfl_xor(sum, 32);
    const float inv = 1.0f / sum;
    // packed b64 write: chunk = i*2+(lg>>1), off = (lg&1)*4 + r
#pragma unroll
    for (int i = 0; i < 4; i++) {
      uint2 w;
      w.x = (unsigned)f2bf(l[i][0] * inv) | ((unsigned)f2bf(l[i][1] * inv) << 16);
      w.y = (unsigned)f2bf(l[i][2] * inv) | ((unsigned)f2bf(l[i][3] * inv) << 16);
      int idx = ((i * 2 + (lg >> 1)) * 64 + b) * 8 + (lg & 1) * 4;
      *(uint2*)&P[idx] = w;
    }
  }

  // --- O = P·V : A-frags of P (b128), B-frags = V^T gathered from LDS ---
  f32x4 o[4][2];
#pragma unroll
  for (int i = 0; i < 4; i++) { o[i][0] = z4; o[i][1] = z4; }
#pragma unroll
  for (int ks = 0; ks < 2; ks++) {
    bf16x8 ap[4], bv[2];
#pragma unroll
    for (int i = 0; i < 4; i++)
      ap[i] = *(const bf16x8*)&P[((ks * 4 + lg) * 64 + i * 16 + lm) * 8];
#pragma unroll
    for (int jj = 0; jj < 2; jj++) {
      bf16x8 bt;
#pragma unroll
      for (int t = 0; t < 8; t++)
        bt[t] = (short)V[(ks * 32 + lg * 8 + t) * 40 + jj * 16 + lm];
      bv[jj] = bt;
    }
#pragma unroll
    for (int i = 0; i < 4; i++)
#pragma unroll
      for (int jj = 0; jj < 2; jj++)
        o[i][jj] = __builtin_amdgcn_mfma_f32_16x16x32_bf16(ap[i], bv[jj], o[i][jj], 0, 0, 0);
  }

  // --- store (C-layout: row b = i*16+lg*4+r, col d = jj*16+lm) ---
#pragma unroll
  for (int i = 0; i < 4; i++) {
#pragma unroll
    for (int r = 0; r < 4; r++) {
      int b = i * 16 + lg * 4 + r;
      if (b < NTOK) {
#pragma unroll
        for (int jj = 0; jj < 2; jj++)
          *(unsigned short*)&attn[obase + (long)b * CDIM + h * 32 + jj * 16 + lm] =
              f2bf(o[i][jj][r]);
      }
    }
  }
}

// ---------- launch ----------
extern "C" void kernel_launch(void* const* d_in, const int* in_sizes, int n_in,
                              void* d_out, int out_size, void* d_ws, size_t ws_size,
                              hipStream_t stream) {
  (void)in_sizes; (void)n_in; (void)out_size; (void)ws_size;
  const float* x          = (const float*)d_in[0];
  const float* w_qkv      = (const float*)d_in[1];
  const float* b_qkv      = (const float*)d_in[2];
  const float* w_proj     = (const float*)d_in[3];
  const float* b_proj     = (const float*)d_in[4];
  const float* bias_table = (const float*)d_in[5];
  float* out = (float*)d_out;

  // workspace layout (bytes):
  //   qkv     [200704][1152] bf16 : 0          .. 462422016
  //   xb/attn [200704][ 384] bf16 : 462422016  .. 616562688   (aliased)
  //   wqkv_t  [1152][384]    bf16 : 616562688  .. 617447424
  //   wproj_t [ 384][384]    bf16 : 617447424  .. 617742336
  //   bias_p  [12][64][64]   f32  : 617742336  .. 617938944
  char* ws = (char*)d_ws;
  __hip_bfloat16* qkv     = (__hip_bfloat16*)(ws);
  __hip_bfloat16* xb      = (__hip_bfloat16*)(ws + 462422016L);
  __hip_bfloat16* attn    = xb;
  __hip_bfloat16* wqkv_t  = (__hip_bfloat16*)(ws + 616562688L);
  __hip_bfloat16* wproj_t = (__hip_bfloat16*)(ws + 617447424L);
  float*          bias_p  = (float*)(ws + 617742336L);

  cvt_x_kernel<<<75264, 256, 0, stream>>>((const float4*)x, (ushort4*)xb, 19267584);
  cvt_small_kernel<<<2496, 256, 0, stream>>>(w_qkv, w_proj, bias_table, wqkv_t, wproj_t, bias_p);
  gemm_bt_kernel<__hip_bfloat16, 9><<<dim3(576, 25), 256, 0, stream>>>(xb, wqkv_t, b_qkv, qkv, NQKV);
  attn_kernel<<<12288, 256, 0, stream>>>(qkv, bias_p, attn);
  gemm_bt_kernel<float, 3><<<dim3(192, 25), 256, 0, stream>>>(attn, wproj_t, b_proj, out, CDIM);
}